// Round 11
// baseline (227.277 us; speedup 1.0000x reference)
//
#include <hip/hip_runtime.h>

#define NQ 10000
#define BS 2
#define NV 19560
#define NH 8
#define HD 32
#define EMB 256

typedef __attribute__((ext_vector_type(8))) short bf16x8;
typedef __attribute__((ext_vector_type(4))) float f32x4;
typedef __attribute__((ext_vector_type(4))) short s16x4;

__device__ __forceinline__ unsigned short f2bf(float x) {
    unsigned u = __float_as_uint(x);
    u += 0x7FFFu + ((u >> 16) & 1u);       // RNE
    return (unsigned short)(u >> 16);
}
__device__ __forceinline__ float bf2f(unsigned short h) {
    return __uint_as_float(((unsigned)h) << 16);
}

// ---------------------------------------------------------------------------
// Transpose weights into Bt[n][k] bf16 (rows 0-255 W_val, 256-511 W_off,
// 512-639 W_attn) + concat biases. Tiny one-shot kernel. [proven]
// ---------------------------------------------------------------------------
__global__ __launch_bounds__(256) void convert_W(
    const float* __restrict__ Wv, const float* __restrict__ Wo,
    const float* __restrict__ Wa, const float* __restrict__ bv,
    const float* __restrict__ bo, const float* __restrict__ ba,
    ushort* __restrict__ Bt, float* __restrict__ bias) {
    int n = blockIdx.x;      // 0..639
    int k = threadIdx.x;     // 0..255
    float x;
    if (n < 256)       x = Wv[k * 256 + n];
    else if (n < 512)  x = Wo[k * 256 + (n - 256)];
    else               x = Wa[k * 128 + (n - 512)];
    Bt[n * 256 + k] = f2bf(x);
    if (k == 0)
        bias[n] = (n < 256) ? bv[n] : (n < 512) ? bo[n - 256] : ba[n - 512];
}

// ---------------------------------------------------------------------------
// Fused GEMM, one dispatch for both projections. [round-10 PROVEN, verbatim]
// 64m x 128n tile, 4 waves (wave tile 32m x 64n = 2x4 of 16x16x32 MFMA),
// 2-barrier BK=32 k-loop, ~8 blocks/CU hide barrier drains.
// blockIdx < 1224: value-proj -> planar bf16. Else: query-proj -> fp32.
// ---------------------------------------------------------------------------
__global__ __launch_bounds__(256) void gemm_fused(
    const float* __restrict__ value, const float* __restrict__ query,
    const float* __restrict__ qpos, const ushort* __restrict__ Bt,
    const float* __restrict__ bias,
    ushort* __restrict__ Cv, float* __restrict__ C0, float* __restrict__ C1)
{
    __shared__ short As[64][40], Bhs[128][40];  // pad 32->40

    const int tid = threadIdx.x;
    const int bid = blockIdx.x;
    bool isval; int mblk, npan;
    if (bid < 1224) { isval = true;  mblk = bid >> 1; npan = bid & 1; }
    else { int q = bid - 1224; isval = false; mblk = q / 3; npan = q % 3; }

    const int M  = isval ? (BS * NV) : (BS * NQ);
    const int m0 = mblk * 64;
    const int n0 = npan * 128;
    const int nbase = (isval ? 0 : 256) + n0;

    const float* A = isval ? value : query;

    const int arow = tid >> 2;
    const int acol = (tid & 3) * 8;
    const bool aval = (m0 + arow) < M;
    const float* Ap  = A    + (size_t)(m0 + arow) * 256 + acol;
    const float* A2p = qpos + (size_t)(m0 + arow) * 256 + acol;
    const int brow = tid >> 1;
    const int bcol = (tid & 1) * 16;
    const ushort* Bp = Bt + (size_t)(nbase + brow) * 256 + bcol;

    const int lane = tid & 63, wave = tid >> 6;
    const int wrow = (wave >> 1) * 32, wcol = (wave & 1) * 64;
    const int lr = lane & 15, quad = lane >> 4, lk = quad * 8;

    f32x4 acc[2][4] = {};

    for (int k0 = 0; k0 < 256; k0 += 32) {
        #pragma unroll
        for (int g = 0; g < 2; g++) {
            f32x4 v = {};
            if (aval) {
                v = *(const f32x4*)(Ap + k0 + g * 4);
                if (!isval) v += *(const f32x4*)(A2p + k0 + g * 4);
            }
            s16x4 hh;
            #pragma unroll
            for (int e = 0; e < 4; e++) hh[e] = (short)f2bf(v[e]);
            *(s16x4*)&As[arow][acol + g * 4] = hh;
        }
        *(bf16x8*)&Bhs[brow][bcol]     = *(const bf16x8*)(Bp + k0);
        *(bf16x8*)&Bhs[brow][bcol + 8] = *(const bf16x8*)(Bp + k0 + 8);
        __syncthreads();

        bf16x8 af[2], bhf[4];
        #pragma unroll
        for (int i = 0; i < 2; i++)
            af[i] = *(const bf16x8*)&As[wrow + i * 16 + lr][lk];
        #pragma unroll
        for (int j = 0; j < 4; j++)
            bhf[j] = *(const bf16x8*)&Bhs[wcol + j * 16 + lr][lk];
        #pragma unroll
        for (int i = 0; i < 2; i++)
            #pragma unroll
            for (int j = 0; j < 4; j++)
                acc[i][j] = __builtin_amdgcn_mfma_f32_16x16x32_bf16(af[i], bhf[j], acc[i][j], 0, 0, 0);
        __syncthreads();
    }

    #pragma unroll
    for (int j = 0; j < 4; j++) {
        int cc = wcol + j * 16 + lr;
        int col = n0 + cc;
        float bb = bias[nbase + cc];
        #pragma unroll
        for (int i = 0; i < 2; i++) {
            int gmb = m0 + wrow + i * 16 + quad * 4;
            #pragma unroll
            for (int r = 0; r < 4; r++) {
                int gm = gmb + r;
                if (gm < M) {
                    float val = acc[i][j][r] + bb;
                    if (isval) {
                        int h = col >> 5, d = col & 31;
                        int b = (gm >= NV) ? 1 : 0;
                        int pix = gm - b * NV;
                        Cv[((size_t)(b * 8 + h) * NV + pix) * 32 + d] = f2bf(val);
                    } else {
                        if (col < 256) C0[(size_t)gm * 256 + col] = val;
                        else           C1[(size_t)gm * 128 + (col - 256)] = val;
                    }
                }
            }
        }
    }
}

// ---------------------------------------------------------------------------
// Fused softmax + location + bilinear gather. [round-3 PROVEN, verbatim —
// fastest measured sampler: 70.6 µs]. Block = one (b,q), 256 threads.
// Phase 1 (t<128): softmax over 16 logits (shuffle w16) + pixel coords +
// clamped corner offsets + validity-premultiplied weights -> LDS.
// Phase 2: 32 lanes per head, lane = channel, scalar ushort gathers.
// ---------------------------------------------------------------------------
__global__ __launch_bounds__(256) void sample2(
    const ushort* __restrict__ v, const float* __restrict__ off,
    const float* __restrict__ attn, const float* __restrict__ refp,
    float* __restrict__ out)
{
    __shared__ int   s_off[128][5];
    __shared__ float s_w[128][5];

    const int bq = blockIdx.x;
    const int b = (bq >= NQ) ? 1 : 0;
    const int t = threadIdx.x;

    if (t < 128) {
        const int h = t >> 4, i = t & 15, l = i >> 2, p = i & 3;
        float logit = attn[(size_t)bq * 128 + t];
        float mx = logit;
        #pragma unroll
        for (int m = 1; m < 16; m <<= 1) mx = fmaxf(mx, __shfl_xor(mx, m, 16));
        float e = __expf(logit - mx);
        float s = e;
        #pragma unroll
        for (int m = 1; m < 16; m <<= 1) s += __shfl_xor(s, m, 16);
        float w = e / s;

        const float Wf[4] = {160.f, 80.f, 40.f, 20.f};
        const float Hf[4] = {92.f, 46.f, 23.f, 12.f};
        const int   Wi[4] = {160, 80, 40, 20};
        const int   Hi[4] = {92, 46, 23, 12};
        const int   st[4] = {0, 14720, 18400, 19320};

        float ox = off[(size_t)bq * 256 + h * 32 + l * 8 + p * 2];
        float oy = off[(size_t)bq * 256 + h * 32 + l * 8 + p * 2 + 1];
        float rx = refp[(size_t)bq * 8 + p * 2];
        float ry = refp[(size_t)bq * 8 + p * 2 + 1];
        float x = rx * Wf[l] + ox - 0.5f;
        float y = ry * Hf[l] + oy - 0.5f;
        float x0f = floorf(x), y0f = floorf(y);
        float wx1 = x - x0f, wy1 = y - y0f;
        float wx0 = 1.f - wx1, wy0 = 1.f - wy1;
        int x0 = (int)x0f, y0 = (int)y0f;
        const int W = Wi[l], H = Hi[l];
        float mx0 = ((unsigned)x0       < (unsigned)W) ? 1.f : 0.f;
        float mx1 = ((unsigned)(x0 + 1) < (unsigned)W) ? 1.f : 0.f;
        float my0 = ((unsigned)y0       < (unsigned)H) ? 1.f : 0.f;
        float my1 = ((unsigned)(y0 + 1) < (unsigned)H) ? 1.f : 0.f;
        int xc0 = min(max(x0, 0), W - 1);
        int xc1 = min(max(x0 + 1, 0), W - 1);
        int yc0 = min(max(y0, 0), H - 1);
        int yc1 = min(max(y0 + 1, 0), H - 1);
        int base = ((b * 8 + h) * NV + st[l]) * 32;
        s_off[t][0] = base + (yc0 * W + xc0) * 32;
        s_off[t][1] = base + (yc0 * W + xc1) * 32;
        s_off[t][2] = base + (yc1 * W + xc0) * 32;
        s_off[t][3] = base + (yc1 * W + xc1) * 32;
        s_w[t][0] = w * wy0 * wx0 * my0 * mx0;
        s_w[t][1] = w * wy0 * wx1 * my0 * mx1;
        s_w[t][2] = w * wy1 * wx0 * my1 * mx0;
        s_w[t][3] = w * wy1 * wx1 * my1 * mx1;
    }
    __syncthreads();

    const int h = t >> 5, d = t & 31;
    float acc = 0.f;
    #pragma unroll 4
    for (int i = 0; i < 16; i++) {
        int idx = h * 16 + i;
        int o0 = s_off[idx][0], o1 = s_off[idx][1];
        int o2 = s_off[idx][2], o3 = s_off[idx][3];
        float w0 = s_w[idx][0], w1 = s_w[idx][1];
        float w2 = s_w[idx][2], w3 = s_w[idx][3];
        acc += w0 * bf2f(v[o0 + d]) + w1 * bf2f(v[o1 + d])
             + w2 * bf2f(v[o2 + d]) + w3 * bf2f(v[o3 + d]);
    }
    out[(size_t)bq * 256 + t] = acc;
}

extern "C" void kernel_launch(void* const* d_in, const int* in_sizes, int n_in,
                              void* d_out, int out_size, void* d_ws, size_t ws_size,
                              hipStream_t stream) {
    const float* query     = (const float*)d_in[0];
    const float* value     = (const float*)d_in[1];
    const float* query_pos = (const float*)d_in[2];
    const float* refp      = (const float*)d_in[3];
    const float* W_val     = (const float*)d_in[4];
    const float* b_val     = (const float*)d_in[5];
    const float* W_off     = (const float*)d_in[6];
    const float* b_off     = (const float*)d_in[7];
    const float* W_attn    = (const float*)d_in[8];
    const float* b_attn    = (const float*)d_in[9];
    float* out = (float*)d_out;

    char* w = (char*)d_ws;
    float*  off    = (float*)w;   w += 20480000;   // 20000 x 256 fp32
    float*  attn   = (float*)w;   w += 10240000;   // 20000 x 128 fp32
    ushort* vp_bf  = (ushort*)w;  w += 20029440;   // planar (b,h,NV,32) bf16
    ushort* Bt     = (ushort*)w;  w += 327680;     // 640 x 256 bf16
    float*  bias_c = (float*)w;   w += 2560;

    convert_W<<<640, 256, 0, stream>>>(W_val, W_off, W_attn, b_val, b_off, b_attn,
                                       Bt, bias_c);

    // one dispatch: value-proj (1224 blocks) + query-proj (939 blocks)
    gemm_fused<<<1224 + 939, 256, 0, stream>>>(value, query, query_pos, Bt, bias_c,
                                               vp_bf, off, attn);

    // fused softmax + loc + bilinear sample (1 query per block)
    sample2<<<BS * NQ, 256, 0, stream>>>(vp_bf, off, attn, refp, out);
}

// Round 12
// 222.333 us; speedup vs baseline: 1.0222x; 1.0222x over previous
//
#include <hip/hip_runtime.h>

#define NQ 10000
#define BS 2
#define NV 19560
#define NH 8
#define HD 32
#define EMB 256

typedef __attribute__((ext_vector_type(8))) short bf16x8;
typedef __attribute__((ext_vector_type(4))) float f32x4;
typedef __attribute__((ext_vector_type(4))) short s16x4;

__device__ __forceinline__ unsigned short f2bf(float x) {
    unsigned u = __float_as_uint(x);
    u += 0x7FFFu + ((u >> 16) & 1u);       // RNE
    return (unsigned short)(u >> 16);
}

// ---------------------------------------------------------------------------
// Transpose weights into Bt[n][k] bf16 (rows 0-255 W_val, 256-511 W_off,
// 512-639 W_attn) + concat biases. [r10 proven, verbatim]
// ---------------------------------------------------------------------------
__global__ __launch_bounds__(256) void convert_W(
    const float* __restrict__ Wv, const float* __restrict__ Wo,
    const float* __restrict__ Wa, const float* __restrict__ bv,
    const float* __restrict__ bo, const float* __restrict__ ba,
    ushort* __restrict__ Bt, float* __restrict__ bias) {
    int n = blockIdx.x;      // 0..639
    int k = threadIdx.x;     // 0..255
    float x;
    if (n < 256)       x = Wv[k * 256 + n];
    else if (n < 512)  x = Wo[k * 256 + (n - 256)];
    else               x = Wa[k * 128 + (n - 512)];
    Bt[n * 256 + k] = f2bf(x);
    if (k == 0)
        bias[n] = (n < 256) ? bv[n] : (n < 512) ? bo[n - 256] : ba[n - 512];
}

// ---------------------------------------------------------------------------
// Fused GEMM, one dispatch for both projections. [r10 proven, verbatim]
// ---------------------------------------------------------------------------
__global__ __launch_bounds__(256) void gemm_fused(
    const float* __restrict__ value, const float* __restrict__ query,
    const float* __restrict__ qpos, const ushort* __restrict__ Bt,
    const float* __restrict__ bias,
    ushort* __restrict__ Cv, float* __restrict__ C0, float* __restrict__ C1)
{
    __shared__ short As[64][40], Bhs[128][40];  // pad 32->40

    const int tid = threadIdx.x;
    const int bid = blockIdx.x;
    bool isval; int mblk, npan;
    if (bid < 1224) { isval = true;  mblk = bid >> 1; npan = bid & 1; }
    else { int q = bid - 1224; isval = false; mblk = q / 3; npan = q % 3; }

    const int M  = isval ? (BS * NV) : (BS * NQ);
    const int m0 = mblk * 64;
    const int n0 = npan * 128;
    const int nbase = (isval ? 0 : 256) + n0;

    const float* A = isval ? value : query;

    const int arow = tid >> 2;
    const int acol = (tid & 3) * 8;
    const bool aval = (m0 + arow) < M;
    const float* Ap  = A    + (size_t)(m0 + arow) * 256 + acol;
    const float* A2p = qpos + (size_t)(m0 + arow) * 256 + acol;
    const int brow = tid >> 1;
    const int bcol = (tid & 1) * 16;
    const ushort* Bp = Bt + (size_t)(nbase + brow) * 256 + bcol;

    const int lane = tid & 63, wave = tid >> 6;
    const int wrow = (wave >> 1) * 32, wcol = (wave & 1) * 64;
    const int lr = lane & 15, quad = lane >> 4, lk = quad * 8;

    f32x4 acc[2][4] = {};

    for (int k0 = 0; k0 < 256; k0 += 32) {
        #pragma unroll
        for (int g = 0; g < 2; g++) {
            f32x4 v = {};
            if (aval) {
                v = *(const f32x4*)(Ap + k0 + g * 4);
                if (!isval) v += *(const f32x4*)(A2p + k0 + g * 4);
            }
            s16x4 hh;
            #pragma unroll
            for (int e = 0; e < 4; e++) hh[e] = (short)f2bf(v[e]);
            *(s16x4*)&As[arow][acol + g * 4] = hh;
        }
        *(bf16x8*)&Bhs[brow][bcol]     = *(const bf16x8*)(Bp + k0);
        *(bf16x8*)&Bhs[brow][bcol + 8] = *(const bf16x8*)(Bp + k0 + 8);
        __syncthreads();

        bf16x8 af[2], bhf[4];
        #pragma unroll
        for (int i = 0; i < 2; i++)
            af[i] = *(const bf16x8*)&As[wrow + i * 16 + lr][lk];
        #pragma unroll
        for (int j = 0; j < 4; j++)
            bhf[j] = *(const bf16x8*)&Bhs[wcol + j * 16 + lr][lk];
        #pragma unroll
        for (int i = 0; i < 2; i++)
            #pragma unroll
            for (int j = 0; j < 4; j++)
                acc[i][j] = __builtin_amdgcn_mfma_f32_16x16x32_bf16(af[i], bhf[j], acc[i][j], 0, 0, 0);
        __syncthreads();
    }

    #pragma unroll
    for (int j = 0; j < 4; j++) {
        int cc = wcol + j * 16 + lr;
        int col = n0 + cc;
        float bb = bias[nbase + cc];
        #pragma unroll
        for (int i = 0; i < 2; i++) {
            int gmb = m0 + wrow + i * 16 + quad * 4;
            #pragma unroll
            for (int r = 0; r < 4; r++) {
                int gm = gmb + r;
                if (gm < M) {
                    float val = acc[i][j][r] + bb;
                    if (isval) {
                        int h = col >> 5, d = col & 31;
                        int b = (gm >= NV) ? 1 : 0;
                        int pix = gm - b * NV;
                        Cv[((size_t)(b * 8 + h) * NV + pix) * 32 + d] = f2bf(val);
                    } else {
                        if (col < 256) C0[(size_t)gm * 256 + col] = val;
                        else           C1[(size_t)gm * 128 + (col - 256)] = val;
                    }
                }
            }
        }
    }
}

// ---------------------------------------------------------------------------
// Sampler v6: 8 queries/block. Phase 1 (proven math, 4 reps): one thread per
// (q,h,l,p) point -> softmax (shuffle w16) + pixel coords + clamped corner
// offsets + validity-premultiplied weights into LDS rows of stride 66 dwords
// (66g % 32 = 2g -> 16 distinct banks across a wave's 16 groups; 4-lane
// same-address reads broadcast free). Phase 2: 4 lanes per (q,h), lane = 8
// channels (dwordx4 gathers -> 4x fewer wave-level load insts than sample2);
// 2-point batches keep 8 loads in flight; 8 channel accumulators.
// ---------------------------------------------------------------------------
__global__ __launch_bounds__(256) void sample6(
    const ushort* __restrict__ v, const float* __restrict__ off,
    const float* __restrict__ attn, const float* __restrict__ refp,
    float* __restrict__ out)
{
    __shared__ int   s_off[64][66];
    __shared__ float s_w[64][66];

    const int bq0 = blockIdx.x * 8;
    const int t = threadIdx.x;

    #pragma unroll
    for (int rep = 0; rep < 4; rep++) {
        const int id = rep * 256 + t;      // 0..1023
        const int g = id >> 4;             // group = qi*8 + h
        const int qi = g >> 3, h = g & 7;
        const int bq = bq0 + qi;
        const int b = (bq >= NQ) ? 1 : 0;
        const int i = id & 15;             // point = l*4 + p
        const int l = i >> 2, p = i & 3;

        float logit = attn[(size_t)bq * 128 + h * 16 + i];
        float mx = logit;
        #pragma unroll
        for (int m = 1; m < 16; m <<= 1) mx = fmaxf(mx, __shfl_xor(mx, m, 16));
        float e = __expf(logit - mx);
        float s = e;
        #pragma unroll
        for (int m = 1; m < 16; m <<= 1) s += __shfl_xor(s, m, 16);
        float w = e / s;

        const float Wf[4] = {160.f, 80.f, 40.f, 20.f};
        const float Hf[4] = {92.f, 46.f, 23.f, 12.f};
        const int   Wi[4] = {160, 80, 40, 20};
        const int   Hi[4] = {92, 46, 23, 12};
        const int   st[4] = {0, 14720, 18400, 19320};

        float ox = off[(size_t)bq * 256 + h * 32 + l * 8 + p * 2];
        float oy = off[(size_t)bq * 256 + h * 32 + l * 8 + p * 2 + 1];
        float rx = refp[(size_t)bq * 8 + p * 2];
        float ry = refp[(size_t)bq * 8 + p * 2 + 1];
        float x = rx * Wf[l] + ox - 0.5f;
        float y = ry * Hf[l] + oy - 0.5f;
        float x0f = floorf(x), y0f = floorf(y);
        float wx1 = x - x0f, wy1 = y - y0f;
        float wx0 = 1.f - wx1, wy0 = 1.f - wy1;
        int x0 = (int)x0f, y0 = (int)y0f;
        const int W = Wi[l], H = Hi[l];
        float mx0 = ((unsigned)x0       < (unsigned)W) ? 1.f : 0.f;
        float mx1 = ((unsigned)(x0 + 1) < (unsigned)W) ? 1.f : 0.f;
        float my0 = ((unsigned)y0       < (unsigned)H) ? 1.f : 0.f;
        float my1 = ((unsigned)(y0 + 1) < (unsigned)H) ? 1.f : 0.f;
        int xc0 = min(max(x0, 0), W - 1);
        int xc1 = min(max(x0 + 1, 0), W - 1);
        int yc0 = min(max(y0, 0), H - 1);
        int yc1 = min(max(y0 + 1, 0), H - 1);
        int base = ((b * 8 + h) * NV + st[l]) * 32;
        s_off[g][i * 4 + 0] = base + (yc0 * W + xc0) * 32;
        s_off[g][i * 4 + 1] = base + (yc0 * W + xc1) * 32;
        s_off[g][i * 4 + 2] = base + (yc1 * W + xc0) * 32;
        s_off[g][i * 4 + 3] = base + (yc1 * W + xc1) * 32;
        s_w[g][i * 4 + 0] = w * wy0 * wx0 * my0 * mx0;
        s_w[g][i * 4 + 1] = w * wy0 * wx1 * my0 * mx1;
        s_w[g][i * 4 + 2] = w * wy1 * wx0 * my1 * mx0;
        s_w[g][i * 4 + 3] = w * wy1 * wx1 * my1 * mx1;
    }
    __syncthreads();

    const int g  = t >> 2;          // 0..63: (qi, h)
    const int c4 = t & 3;           // 8-channel slice
    const int qi = g >> 3, h = g & 7;
    const int bq = bq0 + qi;
    const int d8 = c4 * 8;

    float a0=0.f,a1=0.f,a2=0.f,a3=0.f,a4=0.f,a5=0.f,a6=0.f,a7=0.f;
    #pragma unroll
    for (int i = 0; i < 16; i += 2) {       // 2 points = 8 corner loads/batch
        int o[8]; float wgt[8];
        #pragma unroll
        for (int pp = 0; pp < 2; pp++)
            #pragma unroll
            for (int c = 0; c < 4; c++) {
                o[pp * 4 + c]   = s_off[g][(i + pp) * 4 + c];
                wgt[pp * 4 + c] = s_w[g][(i + pp) * 4 + c];
            }
        uint4 u[8];
        #pragma unroll
        for (int j = 0; j < 8; j++)
            u[j] = *(const uint4*)(v + o[j] + d8);
        #pragma unroll
        for (int j = 0; j < 8; j++) {
            float w = wgt[j];
            a0 += w * __uint_as_float(u[j].x << 16);
            a1 += w * __uint_as_float(u[j].x & 0xffff0000u);
            a2 += w * __uint_as_float(u[j].y << 16);
            a3 += w * __uint_as_float(u[j].y & 0xffff0000u);
            a4 += w * __uint_as_float(u[j].z << 16);
            a5 += w * __uint_as_float(u[j].z & 0xffff0000u);
            a6 += w * __uint_as_float(u[j].w << 16);
            a7 += w * __uint_as_float(u[j].w & 0xffff0000u);
        }
    }
    float* op = out + (size_t)bq * 256 + h * 32 + d8;
    f32x4 r0 = {a0, a1, a2, a3};
    f32x4 r1 = {a4, a5, a6, a7};
    *(f32x4*)op       = r0;
    *(f32x4*)(op + 4) = r1;
}

extern "C" void kernel_launch(void* const* d_in, const int* in_sizes, int n_in,
                              void* d_out, int out_size, void* d_ws, size_t ws_size,
                              hipStream_t stream) {
    const float* query     = (const float*)d_in[0];
    const float* value     = (const float*)d_in[1];
    const float* query_pos = (const float*)d_in[2];
    const float* refp      = (const float*)d_in[3];
    const float* W_val     = (const float*)d_in[4];
    const float* b_val     = (const float*)d_in[5];
    const float* W_off     = (const float*)d_in[6];
    const float* b_off     = (const float*)d_in[7];
    const float* W_attn    = (const float*)d_in[8];
    const float* b_attn    = (const float*)d_in[9];
    float* out = (float*)d_out;

    char* w = (char*)d_ws;
    float*  off    = (float*)w;   w += 20480000;   // 20000 x 256 fp32
    float*  attn   = (float*)w;   w += 10240000;   // 20000 x 128 fp32
    ushort* vp_bf  = (ushort*)w;  w += 20029440;   // planar (b,h,NV,32) bf16
    ushort* Bt     = (ushort*)w;  w += 327680;     // 640 x 256 bf16
    float*  bias_c = (float*)w;   w += 2560;

    convert_W<<<640, 256, 0, stream>>>(W_val, W_off, W_attn, b_val, b_off, b_attn,
                                       Bt, bias_c);

    // one dispatch: value-proj (1224 blocks) + query-proj (939 blocks)
    gemm_fused<<<1224 + 939, 256, 0, stream>>>(value, query, query_pos, Bt, bias_c,
                                               vp_bf, off, attn);

    // fused softmax + loc + bilinear sample (8 queries per block)
    sample6<<<BS * NQ / 8, 256, 0, stream>>>(vp_bf, off, attn, refp, out);
}